// Round 7
// baseline (69.962 us; speedup 1.0000x reference)
//
#include <hip/hip_runtime.h>

#define N_NODES 4096
#define BATCH 128
#define SPLITK 8
#define GBN 32                     // GEMM N-tile
#define GBK 64                     // GEMM K-step
#define PITCH 72                   // f16 per LDS row (64 + 8 pad; 144B rows: b128 frag reads conflict-free)
#define KCHUNK (N_NODES / SPLITK)  // 512
#define GEMM_BLOCKS ((N_NODES / GBN) * SPLITK)  // 1024
#define TRANS_BLOCKS (64 * 64)                  // 4096 64x64 tiles

typedef _Float16 f16x4 __attribute__((ext_vector_type(4)));
typedef _Float16 f16x8 __attribute__((ext_vector_type(8)));
typedef float f32x4 __attribute__((ext_vector_type(4)));

// fp8 connT if the HW cvt builtins exist; else bf16 connT.
#if defined(__has_builtin)
#if __has_builtin(__builtin_amdgcn_cvt_f32_fp8) && __has_builtin(__builtin_amdgcn_cvt_pk_fp8_f32)
#define CONN_FP8 1
#endif
#endif
#ifndef CONN_FP8
#define CONN_FP8 0
#endif

#if CONN_FP8
#define CONN_ELEM_BYTES 1
#define CONN_SCALE (1.0f / 256.0f)
#else
#define CONN_ELEM_BYTES 2
#define CONN_SCALE 1.0f
#endif

__device__ __forceinline__ void conn_store4(void* out, size_t off, float4 v) {
#if CONN_FP8
  unsigned int p = __builtin_amdgcn_cvt_pk_fp8_f32(v.x * 256.0f, v.y * 256.0f, 0, false);
  p = (unsigned int)__builtin_amdgcn_cvt_pk_fp8_f32(v.z * 256.0f, v.w * 256.0f, (int)p, true);
  *(unsigned int*)((unsigned char*)out + off) = p;
#else
  const unsigned int ux = __float_as_uint(v.x), uy = __float_as_uint(v.y);
  const unsigned int uz = __float_as_uint(v.z), uw = __float_as_uint(v.w);
  ushort4 u;
  u.x = (unsigned short)((ux + 0x7FFFu + ((ux >> 16) & 1u)) >> 16);  // RNE
  u.y = (unsigned short)((uy + 0x7FFFu + ((uy >> 16) & 1u)) >> 16);
  u.z = (unsigned short)((uz + 0x7FFFu + ((uz >> 16) & 1u)) >> 16);
  u.w = (unsigned short)((uw + 0x7FFFu + ((uw >> 16) & 1u)) >> 16);
  *(ushort4*)((unsigned short*)out + off) = u;
#endif
}

// 4 consecutive conn values of row j at node offset t*4 (t = thread id)
__device__ __forceinline__ float4 conn_load4(const void* cT, int j, int t) {
#if CONN_FP8
  const unsigned int c = *(const unsigned int*)((const unsigned char*)cT + ((size_t)j << 12) + t * 4);
  return make_float4(__builtin_amdgcn_cvt_f32_fp8(c, 0), __builtin_amdgcn_cvt_f32_fp8(c, 1),
                     __builtin_amdgcn_cvt_f32_fp8(c, 2), __builtin_amdgcn_cvt_f32_fp8(c, 3));
#else
  const ushort4 c = *(const ushort4*)((const unsigned short*)cT + ((size_t)j << 12) + t * 4);
  return make_float4(__uint_as_float((unsigned int)c.x << 16),
                     __uint_as_float((unsigned int)c.y << 16),
                     __uint_as_float((unsigned int)c.z << 16),
                     __uint_as_float((unsigned int)c.w << 16));
#endif
}

// ---------------------------------------------------------------------------
// Fused prep kernel. Role interleave: bid%5==0 -> GEMM (1024 blocks), else
// connT transpose (4096 blocks) — mixes MFMA-heavy and streaming blocks on
// every CU so pipes overlap.
// GEMM: split-f16 MFMA, BM=128, BN=32, BK=64, splitK=8; single LDS buffer,
// 2 barriers/step, depth-2 register ping-pong prefetch (160B/thread/step).
// ---------------------------------------------------------------------------
struct GemmSmem {
  alignas(16) _Float16 Ah[128 * PITCH];
  alignas(16) _Float16 Al[128 * PITCH];
  alignas(16) _Float16 Bh[GBN * PITCH];
  alignas(16) _Float16 Bl[GBN * PITCH];
};  // 46080 B -> 3 blocks/CU
struct TransSmem { float tile[64][65]; };
union PrepSmem { GemmSmem g; TransSmem t; };

__global__ __launch_bounds__(256) void fused_prep_kernel(const float* __restrict__ A,
                                                         const float* __restrict__ W,
                                                         const float* __restrict__ conn,
                                                         float* __restrict__ P,
                                                         void* __restrict__ connT,
                                                         unsigned int* __restrict__ maxslot) {
  __shared__ PrepSmem sm;
  const int tid = threadIdx.x;
  const int bid = blockIdx.x;

  if (bid % 5 == 0) {
    // ---------------- GEMM role ----------------
    const int gb = bid / 5;  // 0..1023
    if (gb == 0 && tid == 0) *maxslot = 0u;
    const int wave = tid >> 6, lane = tid & 63;
    const int wm = wave >> 1, wn = wave & 1;    // 2x2 wave grid: 64 rows x 16 cols each
    const int g = lane >> 4, lrow = lane & 15;  // frag lane coords
    const int n0 = (gb & 127) * GBN;
    const int kb = (gb >> 7) * KCHUNK;
    const int ar = tid >> 4;         // A stage base row 0..15 (+16*i)
    const int ac = (tid & 15) * 4;   // A stage col (f32, 0..60)
    const int wr = tid >> 3;         // W stage row 0..31
    const int wc = (tid & 7) * 4;    // W stage col (0..28, +32*i)

    const float* Abase = A + (size_t)ar * N_NODES + kb + ac;
    const float* Wbase = W + (size_t)(n0 + wr) * N_NODES + kb + wc;

    f32x4 acc[4] = {};
    float4 avA[8], avB[8], wvA[2], wvB[2];
#pragma unroll
    for (int i = 0; i < 8; ++i) avA[i] = *(const float4*)(Abase + (size_t)(16 * i) * N_NODES);
#pragma unroll
    for (int i = 0; i < 2; ++i) wvA[i] = *(const float4*)(Wbase + 32 * i);
#pragma unroll
    for (int i = 0; i < 8; ++i) avB[i] = *(const float4*)(Abase + (size_t)(16 * i) * N_NODES + GBK);
#pragma unroll
    for (int i = 0; i < 2; ++i) wvB[i] = *(const float4*)(Wbase + 32 * i + GBK);

    // one K-step: barrier; convert regs->LDS; issue loads for tile t+2;
    // barrier; ds_read frags; 24 MFMA. Load->use distance ~2 step-walls.
    auto step = [&](float4 (&av)[8], float4 (&wv)[2], int knext) {
      __syncthreads();  // previous step's frag reads complete
#pragma unroll
      for (int i = 0; i < 8; ++i) {
        const int row = ar + 16 * i;
        f16x4 hi, lo;
        const float x0 = av[i].x * 256.f, x1 = av[i].y * 256.f,
                    x2 = av[i].z * 256.f, x3 = av[i].w * 256.f;
        hi[0] = (_Float16)x0; lo[0] = (_Float16)(x0 - (float)hi[0]);
        hi[1] = (_Float16)x1; lo[1] = (_Float16)(x1 - (float)hi[1]);
        hi[2] = (_Float16)x2; lo[2] = (_Float16)(x2 - (float)hi[2]);
        hi[3] = (_Float16)x3; lo[3] = (_Float16)(x3 - (float)hi[3]);
        *(f16x4*)&sm.g.Ah[row * PITCH + ac] = hi;
        *(f16x4*)&sm.g.Al[row * PITCH + ac] = lo;
      }
#pragma unroll
      for (int i = 0; i < 2; ++i) {
        f16x4 hi, lo;
        const float x0 = wv[i].x * 64.f, x1 = wv[i].y * 64.f,
                    x2 = wv[i].z * 64.f, x3 = wv[i].w * 64.f;
        hi[0] = (_Float16)x0; lo[0] = (_Float16)(x0 - (float)hi[0]);
        hi[1] = (_Float16)x1; lo[1] = (_Float16)(x1 - (float)hi[1]);
        hi[2] = (_Float16)x2; lo[2] = (_Float16)(x2 - (float)hi[2]);
        hi[3] = (_Float16)x3; lo[3] = (_Float16)(x3 - (float)hi[3]);
        *(f16x4*)&sm.g.Bh[wr * PITCH + wc + 32 * i] = hi;
        *(f16x4*)&sm.g.Bl[wr * PITCH + wc + 32 * i] = lo;
      }
      // depth-2 prefetch (wrap on tail is L2-hot, harmless)
#pragma unroll
      for (int i = 0; i < 8; ++i)
        av[i] = *(const float4*)(Abase + (size_t)(16 * i) * N_NODES + knext);
#pragma unroll
      for (int i = 0; i < 2; ++i) wv[i] = *(const float4*)(Wbase + 32 * i + knext);

      __syncthreads();

#pragma unroll
      for (int kk = 0; kk < 2; ++kk) {
        const int ko = kk * 32 + g * 8;
        f16x8 ah[4], al[4], bh, bl;
#pragma unroll
        for (int fm = 0; fm < 4; ++fm) {
          const int m = wm * 64 + fm * 16 + lrow;
          ah[fm] = *(const f16x8*)&sm.g.Ah[m * PITCH + ko];
          al[fm] = *(const f16x8*)&sm.g.Al[m * PITCH + ko];
        }
        const int nn = wn * 16 + lrow;
        bh = *(const f16x8*)&sm.g.Bh[nn * PITCH + ko];
        bl = *(const f16x8*)&sm.g.Bl[nn * PITCH + ko];
#pragma unroll
        for (int fm = 0; fm < 4; ++fm) {
          acc[fm] = __builtin_amdgcn_mfma_f32_16x16x32_f16(ah[fm], bh, acc[fm], 0, 0, 0);
          acc[fm] = __builtin_amdgcn_mfma_f32_16x16x32_f16(ah[fm], bl, acc[fm], 0, 0, 0);
          acc[fm] = __builtin_amdgcn_mfma_f32_16x16x32_f16(al[fm], bh, acc[fm], 0, 0, 0);
        }
      }
    };

#pragma unroll
    for (int it = 0; it < KCHUNK / GBK; it += 2) {
      step(avA, wvA, ((it + 2) * GBK) & (KCHUNK - 1));
      step(avB, wvB, ((it + 3) * GBK) & (KCHUNK - 1));
    }

    // epilogue: D row = (lane>>4)*4 + reg, col = lane&15 (HW-verified)
    constexpr float INV = 1.0f / 16384.0f;  // 1/(256*64)
    float* Pb = P + (size_t)(gb >> 7) * BATCH * N_NODES;
    const int n = n0 + wn * 16 + lrow;
#pragma unroll
    for (int fm = 0; fm < 4; ++fm)
#pragma unroll
      for (int reg = 0; reg < 4; ++reg) {
        const int m = wm * 64 + fm * 16 + g * 4 + reg;
        Pb[(size_t)m * N_NODES + n] = acc[fm][reg] * INV;
      }
  } else {
    // ---------------- transpose role: connT[j][i] = enc(conn[i][j]) ----------
    const int idx = bid - bid / 5 - 1;       // 0..4095
    const int bx = idx & 63, by = idx >> 6;  // 64x64 tile coords
    const int tx = tid & 15, ty = tid >> 4;  // 16 x 16
#pragma unroll
    for (int r = 0; r < 4; ++r) {
      const float4 v =
          *(const float4*)(conn + (size_t)(by * 64 + ty + 16 * r) * N_NODES + bx * 64 + tx * 4);
      sm.t.tile[ty + 16 * r][tx * 4 + 0] = v.x;
      sm.t.tile[ty + 16 * r][tx * 4 + 1] = v.y;
      sm.t.tile[ty + 16 * r][tx * 4 + 2] = v.z;
      sm.t.tile[ty + 16 * r][tx * 4 + 3] = v.w;
    }
    __syncthreads();
#pragma unroll
    for (int r = 0; r < 4; ++r) {
      const int orow = ty + 16 * r;
      float4 v;
      v.x = sm.t.tile[tx * 4 + 0][orow];
      v.y = sm.t.tile[tx * 4 + 1][orow];
      v.z = sm.t.tile[tx * 4 + 2][orow];
      v.w = sm.t.tile[tx * 4 + 3][orow];
      conn_store4(connT, (size_t)(bx * 64 + orow) * N_NODES + by * 64 + tx * 4, v);
    }
  }
}

// ---------------------------------------------------------------------------
// Fallback-only f32 VALU GEMM (no workspace): P[m][n] = sum_k A[m][k]*W[n][k]
// ---------------------------------------------------------------------------
__global__ __launch_bounds__(256) void proj_gemm_valu(const float* __restrict__ A,
                                                      const float* __restrict__ W,
                                                      float* __restrict__ P,
                                                      unsigned int* __restrict__ maxslot) {
  if (blockIdx.x == 0 && threadIdx.x == 0) *maxslot = 0u;
  __shared__ float As[16][132];
  __shared__ float Bs[16][68];
  const int tid = threadIdx.x;
  const int n0 = blockIdx.x * 64;
  const int tx = tid & 15, ty = tid >> 4;
  const int arow = tid >> 1, acol = (tid & 1) * 8;
  const int brow = tid >> 2, bcol = (tid & 3) * 4;
  float acc[2][4][4] = {};
  const float* Aptr = A + (size_t)arow * N_NODES + acol;
  const float* Wptr = W + (size_t)(n0 + brow) * N_NODES + bcol;
  for (int k0 = 0; k0 < N_NODES; k0 += 16) {
    const float4 a0 = *(const float4*)(Aptr + k0);
    const float4 a1 = *(const float4*)(Aptr + k0 + 4);
    const float4 bv = *(const float4*)(Wptr + k0);
    __syncthreads();
    As[acol + 0][arow] = a0.x; As[acol + 1][arow] = a0.y;
    As[acol + 2][arow] = a0.z; As[acol + 3][arow] = a0.w;
    As[acol + 4][arow] = a1.x; As[acol + 5][arow] = a1.y;
    As[acol + 6][arow] = a1.z; As[acol + 7][arow] = a1.w;
    Bs[bcol + 0][brow] = bv.x; Bs[bcol + 1][brow] = bv.y;
    Bs[bcol + 2][brow] = bv.z; Bs[bcol + 3][brow] = bv.w;
    __syncthreads();
#pragma unroll
    for (int kk = 0; kk < 16; ++kk) {
      const float4 av0 = *(const float4*)&As[kk][ty * 4];
      const float4 av1 = *(const float4*)&As[kk][64 + ty * 4];
      const float4 bv4 = *(const float4*)&Bs[kk][tx * 4];
      const float am[8] = {av0.x, av0.y, av0.z, av0.w, av1.x, av1.y, av1.z, av1.w};
      const float bn[4] = {bv4.x, bv4.y, bv4.z, bv4.w};
#pragma unroll
      for (int i2 = 0; i2 < 2; ++i2)
#pragma unroll
        for (int i = 0; i < 4; ++i)
#pragma unroll
          for (int j = 0; j < 4; ++j)
            acc[i2][i][j] += am[i2 * 4 + i] * bn[j];
    }
  }
#pragma unroll
  for (int i2 = 0; i2 < 2; ++i2)
#pragma unroll
    for (int i = 0; i < 4; ++i) {
      const int m = i2 * 64 + ty * 4 + i;
      *(float4*)(P + (size_t)m * N_NODES + n0 + tx * 4) =
          make_float4(acc[i2][i][0], acc[i2][i][1], acc[i2][i][2], acc[i2][i][3]);
    }
}

__global__ __launch_bounds__(256) void bias_inplace_kernel(float* __restrict__ P,
                                                           const float* __restrict__ bias) {
  const size_t base = ((size_t)blockIdx.x * 256 + threadIdx.x) * 4;
  const int n = (int)(base & (N_NODES - 1));
  float4 s = *(const float4*)(P + base);
  const float4 bv = *(const float4*)(bias + n);
  s.x += bv.x; s.y += bv.y; s.z += bv.z; s.w += bv.w;
  *(float4*)(P + base) = s;
}

// ---------------------------------------------------------------------------
// One workgroup per sample; state in registers (1024 thr x float4).
// MODE 1: prologue reduces NSPLIT GEMM partials + bias; ordered active-list
//         gather over encoded connT rows, 8-way unrolled.
// MODE 0: proj precomputed; f32 conn column gather (fallback).
// ---------------------------------------------------------------------------
template <int MODE, int NSPLIT>
__global__ __launch_bounds__(1024) void avalanche_kernel(const float* __restrict__ Pin,
                                                         const float* __restrict__ bias,
                                                         const void* __restrict__ connv,
                                                         float* __restrict__ out,
                                                         unsigned int* __restrict__ maxslot) {
  const int b = blockIdx.x;
  const int t = threadIdx.x;
  __shared__ unsigned long long mask[64];
  __shared__ int wincl[64];
  __shared__ int list[N_NODES];

  float4 s;
  if (MODE == 1) {
    const float4 bv = *(const float4*)(bias + t * 4);
    s = bv;
#pragma unroll
    for (int sp = 0; sp < NSPLIT; ++sp) {
      const float4 v = *(const float4*)(Pin + (size_t)sp * BATCH * N_NODES +
                                        (size_t)b * N_NODES + t * 4);
      s.x += v.x; s.y += v.y; s.z += v.z; s.w += v.w;
    }
  } else {
    s = *(const float4*)(Pin + (size_t)b * N_NODES + t * 4);
  }

  float total = 0.0f;

  for (int it = 0; it < 100; ++it) {
    const float v0 = s.x, v1 = s.y, v2 = s.z, v3 = s.w;
    unsigned int bits = 0;
    if (v0 > 1.0f) bits |= 1u;
    if (v1 > 1.0f) bits |= 2u;
    if (v2 > 1.0f) bits |= 4u;
    if (v3 > 1.0f) bits |= 8u;

    __syncthreads();
    if (t < 64) mask[t] = 0ULL;
    __syncthreads();
    if (bits) atomicOr(&mask[t >> 4], (unsigned long long)bits << ((t & 15) * 4));
    __syncthreads();

    if (t < 64) {
      int incl = __popcll(mask[t]);
#pragma unroll
      for (int d = 1; d < 64; d <<= 1) {
        const int y = __shfl_up(incl, d);
        if (t >= d) incl += y;
      }
      wincl[t] = incl;
    }
    __syncthreads();
    const int n = wincl[63];
    if (n == 0) break;  // sticky done: state frozen
    total += (float)n;

    if (t < 64) {
      unsigned long long m = mask[t];
      int o = wincl[t] - __popcll(m);
      while (m) {
        list[o++] = (t << 6) + __builtin_ctzll(m);
        m &= m - 1;
      }
    }
    __syncthreads();

    float4 a0 = make_float4(0.f, 0.f, 0.f, 0.f), a1 = a0, a2 = a0, a3 = a0;
    if (MODE == 1) {
      int idx = 0;
      for (; idx + 8 <= n; idx += 8) {
        const float4 c0 = conn_load4(connv, list[idx + 0], t);
        const float4 c1 = conn_load4(connv, list[idx + 1], t);
        const float4 c2 = conn_load4(connv, list[idx + 2], t);
        const float4 c3 = conn_load4(connv, list[idx + 3], t);
        const float4 c4 = conn_load4(connv, list[idx + 4], t);
        const float4 c5 = conn_load4(connv, list[idx + 5], t);
        const float4 c6 = conn_load4(connv, list[idx + 6], t);
        const float4 c7 = conn_load4(connv, list[idx + 7], t);
        a0.x += c0.x; a0.y += c0.y; a0.z += c0.z; a0.w += c0.w;
        a1.x += c1.x; a1.y += c1.y; a1.z += c1.z; a1.w += c1.w;
        a2.x += c2.x; a2.y += c2.y; a2.z += c2.z; a2.w += c2.w;
        a3.x += c3.x; a3.y += c3.y; a3.z += c3.z; a3.w += c3.w;
        a0.x += c4.x; a0.y += c4.y; a0.z += c4.z; a0.w += c4.w;
        a1.x += c5.x; a1.y += c5.y; a1.z += c5.z; a1.w += c5.w;
        a2.x += c6.x; a2.y += c6.y; a2.z += c6.z; a2.w += c6.w;
        a3.x += c7.x; a3.y += c7.y; a3.z += c7.z; a3.w += c7.w;
      }
      for (; idx < n; ++idx) {
        const float4 c = conn_load4(connv, list[idx], t);
        a0.x += c.x; a0.y += c.y; a0.z += c.z; a0.w += c.w;
      }
    } else {
      const float* conn = (const float*)connv;
      for (int idx = 0; idx < n; ++idx) {
        const int j = list[idx];
        a0.x += conn[(size_t)(t * 4 + 0) * N_NODES + j];
        a0.y += conn[(size_t)(t * 4 + 1) * N_NODES + j];
        a0.z += conn[(size_t)(t * 4 + 2) * N_NODES + j];
        a0.w += conn[(size_t)(t * 4 + 3) * N_NODES + j];
      }
    }
    const float sc = (MODE == 1) ? CONN_SCALE : 1.0f;
    const float4 acc = make_float4(((a0.x + a1.x) + (a2.x + a3.x)) * sc,
                                   ((a0.y + a1.y) + (a2.y + a3.y)) * sc,
                                   ((a0.z + a1.z) + (a2.z + a3.z)) * sc,
                                   ((a0.w + a1.w) + (a2.w + a3.w)) * sc);

    s.x = (v0 > 1.0f) ? 0.0f : 0.9f * v0 + acc.x;
    s.y = (v1 > 1.0f) ? 0.0f : 0.9f * v1 + acc.y;
    s.z = (v2 > 1.0f) ? 0.0f : 0.9f * v2 + acc.z;
    s.w = (v3 > 1.0f) ? 0.0f : 0.9f * v3 + acc.w;
  }

  *(float4*)(out + (size_t)b * N_NODES + t * 4) = s;
  if (t == 0) atomicMax(maxslot, __float_as_uint(total));  // totals >= 0
}

// ---------------------------------------------------------------------------
extern "C" void kernel_launch(void* const* d_in, const int* in_sizes, int n_in,
                              void* d_out, int out_size, void* d_ws, size_t ws_size,
                              hipStream_t stream) {
  const float* input = (const float*)d_in[0];  // [128,4096]
  const float* W     = (const float*)d_in[1];  // [4096,4096]
  const float* bias  = (const float*)d_in[2];  // [4096]
  const float* conn  = (const float*)d_in[3];  // [4096,4096]
  float* out = (float*)d_out;                  // [128*4096] state + [1] max_size

  const size_t connT_bytes = (size_t)N_NODES * N_NODES * CONN_ELEM_BYTES;
  const size_t part_bytes  = (size_t)SPLITK * BATCH * N_NODES * sizeof(float);  // 16 MB
  unsigned int* maxslot = (unsigned int*)(out + (size_t)BATCH * N_NODES);

  if (ws_size >= connT_bytes + part_bytes) {
    void* connT = d_ws;
    float* part = (float*)((char*)d_ws + connT_bytes);
    fused_prep_kernel<<<GEMM_BLOCKS + TRANS_BLOCKS, 256, 0, stream>>>(input, W, conn, part,
                                                                      connT, maxslot);
    avalanche_kernel<1, SPLITK><<<BATCH, 1024, 0, stream>>>(part, bias, connT, out, maxslot);
  } else {
    // Fallback: no workspace — f32 GEMM into d_out, in-place bias, strided gather.
    proj_gemm_valu<<<dim3(N_NODES / 64, 1), 256, 0, stream>>>(input, W, out, maxslot);
    bias_inplace_kernel<<<BATCH * N_NODES / 1024, 256, 0, stream>>>(out, bias);
    avalanche_kernel<0, 1><<<BATCH, 1024, 0, stream>>>(out, nullptr, conn, out, maxslot);
  }
}

// Round 8
// 67.907 us; speedup vs baseline: 1.0303x; 1.0303x over previous
//
#include <hip/hip_runtime.h>

#define N_NODES 4096
#define BATCH 128
#define SPLITK 8
#define GBN 32                     // GEMM N-tile
#define GBK 64                     // GEMM K-step (f16 elems)
#define KCHUNK (N_NODES / SPLITK)  // 512
#define NSTEP (KCHUNK / GBK)       // 8
#define GEMM_BLOCKS ((N_NODES / GBN) * SPLITK)  // 1024
#define TRANS_BLOCKS (64 * 64)                  // 4096 64x64 tiles

typedef _Float16 f16x4 __attribute__((ext_vector_type(4)));
typedef _Float16 f16x8 __attribute__((ext_vector_type(8)));
typedef float f32x4 __attribute__((ext_vector_type(4)));
typedef unsigned int u32x4 __attribute__((ext_vector_type(4)));

// ---- async global->LDS (dest = wave-uniform base + lane*16; src per-lane) ----
__device__ __forceinline__ void dma16(const void* g, void* l) {
#if defined(__has_builtin) && __has_builtin(__builtin_amdgcn_global_load_lds)
  __builtin_amdgcn_global_load_lds((const __attribute__((address_space(1))) void*)g,
                                   (__attribute__((address_space(3))) void*)l, 16, 0, 0);
#else
  *(u32x4*)l = *(const u32x4*)g;  // slow-but-correct fallback
#endif
}

// fp8 connT if the HW cvt builtins exist; else bf16 connT.
#if defined(__has_builtin)
#if __has_builtin(__builtin_amdgcn_cvt_f32_fp8) && __has_builtin(__builtin_amdgcn_cvt_pk_fp8_f32)
#define CONN_FP8 1
#endif
#endif
#ifndef CONN_FP8
#define CONN_FP8 0
#endif

#if CONN_FP8
#define CONN_ELEM_BYTES 1
#define CONN_SCALE (1.0f / 256.0f)
#else
#define CONN_ELEM_BYTES 2
#define CONN_SCALE 1.0f
#endif

__device__ __forceinline__ void conn_store4(void* out, size_t off, float4 v) {
#if CONN_FP8
  unsigned int p = __builtin_amdgcn_cvt_pk_fp8_f32(v.x * 256.0f, v.y * 256.0f, 0, false);
  p = (unsigned int)__builtin_amdgcn_cvt_pk_fp8_f32(v.z * 256.0f, v.w * 256.0f, (int)p, true);
  *(unsigned int*)((unsigned char*)out + off) = p;
#else
  const unsigned int ux = __float_as_uint(v.x), uy = __float_as_uint(v.y);
  const unsigned int uz = __float_as_uint(v.z), uw = __float_as_uint(v.w);
  ushort4 u;
  u.x = (unsigned short)((ux + 0x7FFFu + ((ux >> 16) & 1u)) >> 16);  // RNE
  u.y = (unsigned short)((uy + 0x7FFFu + ((uy >> 16) & 1u)) >> 16);
  u.z = (unsigned short)((uz + 0x7FFFu + ((uz >> 16) & 1u)) >> 16);
  u.w = (unsigned short)((uw + 0x7FFFu + ((uw >> 16) & 1u)) >> 16);
  *(ushort4*)((unsigned short*)out + off) = u;
#endif
}

__device__ __forceinline__ float4 conn_load4(const void* cT, int j, int t) {
#if CONN_FP8
  const unsigned int c = *(const unsigned int*)((const unsigned char*)cT + ((size_t)j << 12) + t * 4);
  return make_float4(__builtin_amdgcn_cvt_f32_fp8(c, 0), __builtin_amdgcn_cvt_f32_fp8(c, 1),
                     __builtin_amdgcn_cvt_f32_fp8(c, 2), __builtin_amdgcn_cvt_f32_fp8(c, 3));
#else
  const ushort4 c = *(const ushort4*)((const unsigned short*)cT + ((size_t)j << 12) + t * 4);
  return make_float4(__uint_as_float((unsigned int)c.x << 16),
                     __uint_as_float((unsigned int)c.y << 16),
                     __uint_as_float((unsigned int)c.z << 16),
                     __uint_as_float((unsigned int)c.w << 16));
#endif
}

// ---------------------------------------------------------------------------
// A-split: Ah/Al[128][4096] f16 planes, pre-scaled x256. Also zeroes maxslot.
// ---------------------------------------------------------------------------
__global__ __launch_bounds__(256) void asplit_kernel(const float* __restrict__ in,
                                                     _Float16* __restrict__ Ah,
                                                     _Float16* __restrict__ Al,
                                                     unsigned int* __restrict__ maxslot) {
  if (blockIdx.x == 0 && threadIdx.x == 0) *maxslot = 0u;
  const size_t idx = ((size_t)blockIdx.x * 256 + threadIdx.x) * 4;
  const float4 v = *(const float4*)(in + idx);
  f16x4 hi, lo;
  const float x0 = v.x * 256.f, x1 = v.y * 256.f, x2 = v.z * 256.f, x3 = v.w * 256.f;
  hi[0] = (_Float16)x0; lo[0] = (_Float16)(x0 - (float)hi[0]);
  hi[1] = (_Float16)x1; lo[1] = (_Float16)(x1 - (float)hi[1]);
  hi[2] = (_Float16)x2; lo[2] = (_Float16)(x2 - (float)hi[2]);
  hi[3] = (_Float16)x3; lo[3] = (_Float16)(x3 - (float)hi[3]);
  *(f16x4*)(Ah + idx) = hi;
  *(f16x4*)(Al + idx) = lo;
}

// ---------------------------------------------------------------------------
// Fused: blocks [0,1024) = MFMA GEMM via global_load_lds DMA;
//        blocks [1024, +4096) = connT transpose.
// GEMM: P[s][m][n] = sum_{k in chunk s} A[m][k]*W[n][k], split-f16 3-pass.
// LDS images are XOR-swizzled (byte ^= (row&7)<<4) via pre-swizzled per-lane
// DMA *source* addresses + swizzled ds_reads (linear DMA dest, rule #21).
// ---------------------------------------------------------------------------
struct GemmSmem {
  alignas(16) _Float16 Ah[128 * GBK];  // 16 KB, 128B rows
  alignas(16) _Float16 Al[128 * GBK];  // 16 KB
  alignas(16) float B[GBN * GBK];      // 8 KB, 256B rows (raw f32 W)
};  // 40960 B -> 4 blocks/CU
struct TransSmem { float tile[64][65]; };
union PrepSmem { GemmSmem g; TransSmem t; };

__global__ __launch_bounds__(256, 4) void fused_prep_kernel(
    const _Float16* __restrict__ Ah, const _Float16* __restrict__ Al,
    const float* __restrict__ W, const float* __restrict__ conn,
    float* __restrict__ P, void* __restrict__ connT) {
  __shared__ PrepSmem sm;
  const int tid = threadIdx.x;
  const int bid = blockIdx.x;

  if (bid < GEMM_BLOCKS) {
    // ---------------- GEMM role ----------------
    const int wave = tid >> 6, lane = tid & 63;
    const int wm = wave >> 1, wn = wave & 1;    // 2x2 wave grid
    const int g = lane >> 4, lrow = lane & 15;  // frag lane coords
    const int n0 = (bid & 127) * GBN;
    const int kb = (bid >> 7) * KCHUNK;

    // DMA source terms. A planes: waves 0,1 -> Ah; 2,3 -> Al (8 chunks each).
    const char* AsrcBase = (const char*)((wave >> 1) ? Al : Ah);
    _Float16* AldsBase = (wave >> 1) ? sm.g.Al : sm.g.Ah;
    const int ac0 = (wave & 1) * 8;
    const int arow_l = lane >> 3;                                   // row&7 == this
    const int ainrow = (((lane & 7) << 4) ^ ((lane >> 3) << 4));    // swizzled in-row byte
    const int brow_l = lane >> 4;
    const int binrow0 = (lane & 15) << 4;

    auto issue = [&](int t) {
      const size_t kbyteA = (size_t)(kb + t * GBK) * 2;
      const size_t kbyteB = (size_t)(kb + t * GBK) * 4;
#pragma unroll
      for (int i = 0; i < 8; ++i) {  // A: 8 chunks of 1KB per wave
        const int c = ac0 + i;
        const int row = 8 * c + arow_l;
        dma16(AsrcBase + (size_t)row * (N_NODES * 2) + kbyteA + ainrow,
              (char*)AldsBase + c * 1024 + lane * 16);
      }
#pragma unroll
      for (int i = 0; i < 2; ++i) {  // B: 2 chunks of 1KB per wave
        const int c = wave * 2 + i;
        const int row = 4 * c + brow_l;
        dma16((const char*)W + (size_t)(n0 + row) * (N_NODES * 4) + kbyteB +
                  (binrow0 ^ ((row & 7) << 4)),
              (char*)sm.g.B + c * 1024 + lane * 16);
      }
    };

    f32x4 acc[4] = {};
    issue(0);
    for (int t = 0; t < NSTEP; ++t) {
      __syncthreads();  // DMA of step t drained (compiler emits vmcnt(0))
#pragma unroll
      for (int kk = 0; kk < 2; ++kk) {
        // B frag: 8 f32 -> bh/bl (scale x64), consumer-side split
        const int br = wn * 16 + lrow;
        const char* bbase = (const char*)sm.g.B + br * 256;
        const int bm = (br & 7) << 4;
        const int cb = (kk * 32 + g * 8) * 4;
        const f32x4 b0 = *(const f32x4*)(bbase + ((cb) ^ bm));
        const f32x4 b1 = *(const f32x4*)(bbase + ((cb + 16) ^ bm));
        f16x8 bh, bl;
#pragma unroll
        for (int j = 0; j < 4; ++j) {
          const float x = b0[j] * 64.f;
          const _Float16 h = (_Float16)x;
          bh[j] = h; bl[j] = (_Float16)(x - (float)h);
          const float y = b1[j] * 64.f;
          const _Float16 h2 = (_Float16)y;
          bh[4 + j] = h2; bl[4 + j] = (_Float16)(y - (float)h2);
        }
#pragma unroll
        for (int fm = 0; fm < 4; ++fm) {
          const int ar = wm * 64 + fm * 16 + lrow;
          const int am = (ar & 7) << 4;
          const int ca = (kk * 32 + g * 8) * 2;
          const f16x8 ah = *(const f16x8*)((const char*)sm.g.Ah + ar * 128 + (ca ^ am));
          const f16x8 al = *(const f16x8*)((const char*)sm.g.Al + ar * 128 + (ca ^ am));
          acc[fm] = __builtin_amdgcn_mfma_f32_16x16x32_f16(ah, bh, acc[fm], 0, 0, 0);
          acc[fm] = __builtin_amdgcn_mfma_f32_16x16x32_f16(ah, bl, acc[fm], 0, 0, 0);
          acc[fm] = __builtin_amdgcn_mfma_f32_16x16x32_f16(al, bh, acc[fm], 0, 0, 0);
        }
      }
      __syncthreads();  // all waves done reading this buffer
      if (t + 1 < NSTEP) issue(t + 1);
    }

    // epilogue: D row = (lane>>4)*4 + reg, col = lane&15 (HW-verified)
    constexpr float INV = 1.0f / 16384.0f;  // 1/(256*64)
    float* Pb = P + (size_t)(bid >> 7) * BATCH * N_NODES;
    const int n = n0 + wn * 16 + lrow;
#pragma unroll
    for (int fm = 0; fm < 4; ++fm)
#pragma unroll
      for (int reg = 0; reg < 4; ++reg) {
        const int m = wm * 64 + fm * 16 + g * 4 + reg;
        Pb[(size_t)m * N_NODES + n] = acc[fm][reg] * INV;
      }
  } else {
    // ---------------- transpose role: connT[j][i] = enc(conn[i][j]) ----------
    const int idx = bid - GEMM_BLOCKS;
    const int bx = idx & 63, by = idx >> 6;  // 64x64 tile coords
    const int tx = tid & 15, ty = tid >> 4;  // 16 x 16
#pragma unroll
    for (int r = 0; r < 4; ++r) {
      const float4 v =
          *(const float4*)(conn + (size_t)(by * 64 + ty + 16 * r) * N_NODES + bx * 64 + tx * 4);
      sm.t.tile[ty + 16 * r][tx * 4 + 0] = v.x;
      sm.t.tile[ty + 16 * r][tx * 4 + 1] = v.y;
      sm.t.tile[ty + 16 * r][tx * 4 + 2] = v.z;
      sm.t.tile[ty + 16 * r][tx * 4 + 3] = v.w;
    }
    __syncthreads();
#pragma unroll
    for (int r = 0; r < 4; ++r) {
      const int orow = ty + 16 * r;
      float4 v;
      v.x = sm.t.tile[tx * 4 + 0][orow];
      v.y = sm.t.tile[tx * 4 + 1][orow];
      v.z = sm.t.tile[tx * 4 + 2][orow];
      v.w = sm.t.tile[tx * 4 + 3][orow];
      conn_store4(connT, (size_t)(bx * 64 + orow) * N_NODES + by * 64 + tx * 4, v);
    }
  }
}

// ---------------------------------------------------------------------------
// Fallback-only f32 VALU GEMM (no workspace)
// ---------------------------------------------------------------------------
__global__ __launch_bounds__(256) void proj_gemm_valu(const float* __restrict__ A,
                                                      const float* __restrict__ W,
                                                      float* __restrict__ P,
                                                      unsigned int* __restrict__ maxslot) {
  if (blockIdx.x == 0 && threadIdx.x == 0) *maxslot = 0u;
  __shared__ float As[16][132];
  __shared__ float Bs[16][68];
  const int tid = threadIdx.x;
  const int n0 = blockIdx.x * 64;
  const int tx = tid & 15, ty = tid >> 4;
  const int arow = tid >> 1, acol = (tid & 1) * 8;
  const int brow = tid >> 2, bcol = (tid & 3) * 4;
  float acc[2][4][4] = {};
  const float* Aptr = A + (size_t)arow * N_NODES + acol;
  const float* Wptr = W + (size_t)(n0 + brow) * N_NODES + bcol;
  for (int k0 = 0; k0 < N_NODES; k0 += 16) {
    const float4 a0 = *(const float4*)(Aptr + k0);
    const float4 a1 = *(const float4*)(Aptr + k0 + 4);
    const float4 bv = *(const float4*)(Wptr + k0);
    __syncthreads();
    As[acol + 0][arow] = a0.x; As[acol + 1][arow] = a0.y;
    As[acol + 2][arow] = a0.z; As[acol + 3][arow] = a0.w;
    As[acol + 4][arow] = a1.x; As[acol + 5][arow] = a1.y;
    As[acol + 6][arow] = a1.z; As[acol + 7][arow] = a1.w;
    Bs[bcol + 0][brow] = bv.x; Bs[bcol + 1][brow] = bv.y;
    Bs[bcol + 2][brow] = bv.z; Bs[bcol + 3][brow] = bv.w;
    __syncthreads();
#pragma unroll
    for (int kk = 0; kk < 16; ++kk) {
      const float4 av0 = *(const float4*)&As[kk][ty * 4];
      const float4 av1 = *(const float4*)&As[kk][64 + ty * 4];
      const float4 bv4 = *(const float4*)&Bs[kk][tx * 4];
      const float am[8] = {av0.x, av0.y, av0.z, av0.w, av1.x, av1.y, av1.z, av1.w};
      const float bn[4] = {bv4.x, bv4.y, bv4.z, bv4.w};
#pragma unroll
      for (int i2 = 0; i2 < 2; ++i2)
#pragma unroll
        for (int i = 0; i < 4; ++i)
#pragma unroll
          for (int j = 0; j < 4; ++j)
            acc[i2][i][j] += am[i2 * 4 + i] * bn[j];
    }
  }
#pragma unroll
  for (int i2 = 0; i2 < 2; ++i2)
#pragma unroll
    for (int i = 0; i < 4; ++i) {
      const int m = i2 * 64 + ty * 4 + i;
      *(float4*)(P + (size_t)m * N_NODES + n0 + tx * 4) =
          make_float4(acc[i2][i][0], acc[i2][i][1], acc[i2][i][2], acc[i2][i][3]);
    }
}

__global__ __launch_bounds__(256) void bias_inplace_kernel(float* __restrict__ P,
                                                           const float* __restrict__ bias) {
  const size_t base = ((size_t)blockIdx.x * 256 + threadIdx.x) * 4;
  const int n = (int)(base & (N_NODES - 1));
  float4 s = *(const float4*)(P + base);
  const float4 bv = *(const float4*)(bias + n);
  s.x += bv.x; s.y += bv.y; s.z += bv.z; s.w += bv.w;
  *(float4*)(P + base) = s;
}

// ---------------------------------------------------------------------------
// Avalanche: one workgroup per sample; state in registers.
// ---------------------------------------------------------------------------
template <int MODE, int NSPLIT>
__global__ __launch_bounds__(1024) void avalanche_kernel(const float* __restrict__ Pin,
                                                         const float* __restrict__ bias,
                                                         const void* __restrict__ connv,
                                                         float* __restrict__ out,
                                                         unsigned int* __restrict__ maxslot) {
  const int b = blockIdx.x;
  const int t = threadIdx.x;
  __shared__ unsigned long long mask[64];
  __shared__ int wincl[64];
  __shared__ int list[N_NODES];

  float4 s;
  if (MODE == 1) {
    const float4 bv = *(const float4*)(bias + t * 4);
    s = bv;
#pragma unroll
    for (int sp = 0; sp < NSPLIT; ++sp) {
      const float4 v = *(const float4*)(Pin + (size_t)sp * BATCH * N_NODES +
                                        (size_t)b * N_NODES + t * 4);
      s.x += v.x; s.y += v.y; s.z += v.z; s.w += v.w;
    }
  } else {
    s = *(const float4*)(Pin + (size_t)b * N_NODES + t * 4);
  }

  float total = 0.0f;

  for (int it = 0; it < 100; ++it) {
    const float v0 = s.x, v1 = s.y, v2 = s.z, v3 = s.w;
    unsigned int bits = 0;
    if (v0 > 1.0f) bits |= 1u;
    if (v1 > 1.0f) bits |= 2u;
    if (v2 > 1.0f) bits |= 4u;
    if (v3 > 1.0f) bits |= 8u;

    __syncthreads();
    if (t < 64) mask[t] = 0ULL;
    __syncthreads();
    if (bits) atomicOr(&mask[t >> 4], (unsigned long long)bits << ((t & 15) * 4));
    __syncthreads();

    if (t < 64) {
      int incl = __popcll(mask[t]);
#pragma unroll
      for (int d = 1; d < 64; d <<= 1) {
        const int y = __shfl_up(incl, d);
        if (t >= d) incl += y;
      }
      wincl[t] = incl;
    }
    __syncthreads();
    const int n = wincl[63];
    if (n == 0) break;  // sticky done: state frozen
    total += (float)n;

    if (t < 64) {
      unsigned long long m = mask[t];
      int o = wincl[t] - __popcll(m);
      while (m) {
        list[o++] = (t << 6) + __builtin_ctzll(m);
        m &= m - 1;
      }
    }
    __syncthreads();

    float4 a0 = make_float4(0.f, 0.f, 0.f, 0.f), a1 = a0, a2 = a0, a3 = a0;
    if (MODE == 1) {
      int idx = 0;
      for (; idx + 8 <= n; idx += 8) {
        const float4 c0 = conn_load4(connv, list[idx + 0], t);
        const float4 c1 = conn_load4(connv, list[idx + 1], t);
        const float4 c2 = conn_load4(connv, list[idx + 2], t);
        const float4 c3 = conn_load4(connv, list[idx + 3], t);
        const float4 c4 = conn_load4(connv, list[idx + 4], t);
        const float4 c5 = conn_load4(connv, list[idx + 5], t);
        const float4 c6 = conn_load4(connv, list[idx + 6], t);
        const float4 c7 = conn_load4(connv, list[idx + 7], t);
        a0.x += c0.x; a0.y += c0.y; a0.z += c0.z; a0.w += c0.w;
        a1.x += c1.x; a1.y += c1.y; a1.z += c1.z; a1.w += c1.w;
        a2.x += c2.x; a2.y += c2.y; a2.z += c2.z; a2.w += c2.w;
        a3.x += c3.x; a3.y += c3.y; a3.z += c3.z; a3.w += c3.w;
        a0.x += c4.x; a0.y += c4.y; a0.z += c4.z; a0.w += c4.w;
        a1.x += c5.x; a1.y += c5.y; a1.z += c5.z; a1.w += c5.w;
        a2.x += c6.x; a2.y += c6.y; a2.z += c6.z; a2.w += c6.w;
        a3.x += c7.x; a3.y += c7.y; a3.z += c7.z; a3.w += c7.w;
      }
      for (; idx < n; ++idx) {
        const float4 c = conn_load4(connv, list[idx], t);
        a0.x += c.x; a0.y += c.y; a0.z += c.z; a0.w += c.w;
      }
    } else {
      const float* conn = (const float*)connv;
      for (int idx = 0; idx < n; ++idx) {
        const int j = list[idx];
        a0.x += conn[(size_t)(t * 4 + 0) * N_NODES + j];
        a0.y += conn[(size_t)(t * 4 + 1) * N_NODES + j];
        a0.z += conn[(size_t)(t * 4 + 2) * N_NODES + j];
        a0.w += conn[(size_t)(t * 4 + 3) * N_NODES + j];
      }
    }
    const float sc = (MODE == 1) ? CONN_SCALE : 1.0f;
    const float4 acc = make_float4(((a0.x + a1.x) + (a2.x + a3.x)) * sc,
                                   ((a0.y + a1.y) + (a2.y + a3.y)) * sc,
                                   ((a0.z + a1.z) + (a2.z + a3.z)) * sc,
                                   ((a0.w + a1.w) + (a2.w + a3.w)) * sc);

    s.x = (v0 > 1.0f) ? 0.0f : 0.9f * v0 + acc.x;
    s.y = (v1 > 1.0f) ? 0.0f : 0.9f * v1 + acc.y;
    s.z = (v2 > 1.0f) ? 0.0f : 0.9f * v2 + acc.z;
    s.w = (v3 > 1.0f) ? 0.0f : 0.9f * v3 + acc.w;
  }

  *(float4*)(out + (size_t)b * N_NODES + t * 4) = s;
  if (t == 0) atomicMax(maxslot, __float_as_uint(total));  // totals >= 0
}

// ---------------------------------------------------------------------------
extern "C" void kernel_launch(void* const* d_in, const int* in_sizes, int n_in,
                              void* d_out, int out_size, void* d_ws, size_t ws_size,
                              hipStream_t stream) {
  const float* input = (const float*)d_in[0];  // [128,4096]
  const float* W     = (const float*)d_in[1];  // [4096,4096]
  const float* bias  = (const float*)d_in[2];  // [4096]
  const float* conn  = (const float*)d_in[3];  // [4096,4096]
  float* out = (float*)d_out;                  // [128*4096] state + [1] max_size

  const size_t aplane_bytes = (size_t)BATCH * N_NODES * 2;                       // 1 MB each
  const size_t connT_bytes  = (size_t)N_NODES * N_NODES * CONN_ELEM_BYTES;       // 16/32 MB
  const size_t part_bytes   = (size_t)SPLITK * BATCH * N_NODES * sizeof(float);  // 16 MB
  unsigned int* maxslot = (unsigned int*)(out + (size_t)BATCH * N_NODES);

  if (ws_size >= 2 * aplane_bytes + connT_bytes + part_bytes) {
    _Float16* Ah = (_Float16*)d_ws;
    _Float16* Al = (_Float16*)((char*)d_ws + aplane_bytes);
    void* connT  = (char*)d_ws + 2 * aplane_bytes;
    float* part  = (float*)((char*)d_ws + 2 * aplane_bytes + connT_bytes);
    asplit_kernel<<<BATCH * N_NODES / 1024, 256, 0, stream>>>(input, Ah, Al, maxslot);
    fused_prep_kernel<<<GEMM_BLOCKS + TRANS_BLOCKS, 256, 0, stream>>>(Ah, Al, W, conn, part,
                                                                      connT);
    avalanche_kernel<1, SPLITK><<<BATCH, 1024, 0, stream>>>(part, bias, connT, out, maxslot);
  } else {
    // Fallback: no workspace — f32 GEMM into d_out, in-place bias, strided gather.
    proj_gemm_valu<<<dim3(N_NODES / 64, 1), 256, 0, stream>>>(input, W, out, maxslot);
    bias_inplace_kernel<<<BATCH * N_NODES / 1024, 256, 0, stream>>>(out, bias);
    avalanche_kernel<0, 1><<<BATCH, 1024, 0, stream>>>(out, nullptr, conn, out, maxslot);
  }
}